// Round 2
// baseline (314.303 us; speedup 1.0000x reference)
//
#include <hip/hip_runtime.h>

// PatchTrainer: paint 100 filled circles (last-wins) over a 3x4096x4096 fp32 image.
// Per pixel: out = colors[max covering dot] else patch. Tile-culled, write-streaming.
// R3: nontemporal stores via clang ext_vector_type.
// R4 (resubmit after infra failure): descending-order dot scan + wave-level early
//     exit (last-wins => first hit scanning from highest index). Kills the
//     O(cnt)-per-pixel tail in heavy tiles (cnt up to ~40 centrally; only 4
//     blocks/CU => no work stealing). Plus wave-uniform row cull (y uniform per
//     wave => coherent s_cbranch skip).

#define IMG  4096
#define ND   100
#define TW   256   // tile width  (64 lanes x float4 = one full row per wave)
#define TH   64    // tile height (4 waves, 16 iterations of 4 rows)

typedef float vfloat4 __attribute__((ext_vector_type(4)));  // builtin-compatible

__global__ __launch_bounds__(256) void patch_dots_kernel(
    const float* __restrict__ patch,    // [3][4096][4096]
    const float* __restrict__ centers,  // [100][2] (x, y)
    const float* __restrict__ radii,    // [100]
    const float* __restrict__ colors,   // [100][3]
    float* __restrict__ out)            // [3][4096][4096]
{
    __shared__ float  s_xc[ND], s_yc[ND], s_r2[ND];
    __shared__ float4 s_col[ND];
    __shared__ int    s_flag[ND];
    __shared__ int    s_list[ND];
    __shared__ int    s_cnt;

    const int tx0 = blockIdx.x * TW;
    const int ty0 = blockIdx.y * TH;
    const int t   = threadIdx.x;

    // Stage dot params in LDS + tile-intersection cull.
    if (t < ND) {
        // Bit-exact replication of the reference's fp32 math:
        float xc = floorf(centers[2 * t]     * 4096.0f);
        float yc = floorf(centers[2 * t + 1] * 4096.0f);
        float r  = floorf(radii[t] * (4096.0f / 5.0f));
        float r2 = r * r;
        s_xc[t] = xc; s_yc[t] = yc; s_r2[t] = r2;
        s_col[t] = make_float4(colors[3 * t], colors[3 * t + 1], colors[3 * t + 2], 0.f);
        // Nearest pixel of this tile to the (integer-valued) center:
        float cx = fminf(fmaxf(xc, (float)tx0), (float)(tx0 + TW - 1));
        float cy = fminf(fmaxf(yc, (float)ty0), (float)(ty0 + TH - 1));
        float dx = xc - cx, dy = yc - cy;
        s_flag[t] = (dx * dx + dy * dy <= r2) ? 1 : 0;
    }
    __syncthreads();
    // Ordered compaction (preserves ascending dot index -> descending scan below).
    if (t == 0) {
        int c = 0;
        for (int i = 0; i < ND; ++i)
            if (s_flag[i]) s_list[c++] = i;
        s_cnt = c;
    }
    __syncthreads();
    const int cnt = s_cnt;

    const int lane = t & 63;
    const int w    = t >> 6;
    const int x0   = tx0 + lane * 4;
    const float fx0 = (float)x0;
    const float fx1 = (float)(x0 + 1);
    const float fx2 = (float)(x0 + 2);
    const float fx3 = (float)(x0 + 3);

    for (int it = 0; it < TH / 4; ++it) {
        const int   y  = ty0 + it * 4 + w;
        const float fy = (float)y;

        // Scan dots from HIGHEST index down: first hit == last-drawn winner.
        // Exit as soon as every lane's 4 pixels are resolved.
        int b0 = -1, b1 = -1, b2 = -1, b3 = -1;
        for (int k = cnt - 1; k >= 0; --k) {
            const int   i  = s_list[k];
            const float dy = fy - s_yc[i];
            // hit iff dx*dx <= r2 - dy*dy (exact-integer fp32 region: equivalent
            // to dx*dx + dy*dy <= r2, the reference's comparison)
            const float t2 = s_r2[i] - dy * dy;
            if (t2 < 0.f) continue;          // y uniform per wave -> coherent skip
            const float xc = s_xc[i];
            const float dx0 = fx0 - xc;
            const float dx1 = fx1 - xc;
            const float dx2 = fx2 - xc;
            const float dx3 = fx3 - xc;
            if (b0 < 0 && dx0 * dx0 <= t2) b0 = i;
            if (b1 < 0 && dx1 * dx1 <= t2) b1 = i;
            if (b2 < 0 && dx2 * dx2 <= t2) b2 = i;
            if (b3 < 0 && dx3 * dx3 <= t2) b3 = i;
            // all 4 pixels of all 64 lanes resolved -> done with this row
            if (__all((b0 | b1 | b2 | b3) >= 0)) break;
        }

        const size_t base = (size_t)y * IMG + x0;

        // Patch only needed where no dot covers (rare: ~1.5% of pixels).
        float4 p0 = make_float4(0.f, 0.f, 0.f, 0.f);
        float4 p1 = p0, p2 = p0;
        if ((b0 | b1 | b2 | b3) < 0) {   // any of the 4 pixels uncovered
            p0 = *(const float4*)(patch + base);
            p1 = *(const float4*)(patch + base + (size_t)IMG * IMG);
            p2 = *(const float4*)(patch + base + 2 * (size_t)IMG * IMG);
        }

        // One ds_read_b128 per covered pixel instead of 3 ds_read_b32.
        const float4 c0 = (b0 >= 0) ? s_col[b0] : make_float4(p0.x, p1.x, p2.x, 0.f);
        const float4 c1 = (b1 >= 0) ? s_col[b1] : make_float4(p0.y, p1.y, p2.y, 0.f);
        const float4 c2 = (b2 >= 0) ? s_col[b2] : make_float4(p0.z, p1.z, p2.z, 0.f);
        const float4 c3 = (b3 >= 0) ? s_col[b3] : make_float4(p0.w, p1.w, p2.w, 0.f);

        vfloat4 o0, o1, o2;
        o0.x = c0.x; o0.y = c1.x; o0.z = c2.x; o0.w = c3.x;
        o1.x = c0.y; o1.y = c1.y; o1.z = c2.y; o1.w = c3.y;
        o2.x = c0.z; o2.y = c1.z; o2.z = c2.z; o2.w = c3.z;

        // Nontemporal: write-once stream, keep it out of L2.
        __builtin_nontemporal_store(o0, (vfloat4*)(out + base));
        __builtin_nontemporal_store(o1, (vfloat4*)(out + base + (size_t)IMG * IMG));
        __builtin_nontemporal_store(o2, (vfloat4*)(out + base + 2 * (size_t)IMG * IMG));
    }
}

extern "C" void kernel_launch(void* const* d_in, const int* in_sizes, int n_in,
                              void* d_out, int out_size, void* d_ws, size_t ws_size,
                              hipStream_t stream) {
    const float* patch   = (const float*)d_in[0];
    const float* centers = (const float*)d_in[1];
    const float* radii   = (const float*)d_in[2];
    const float* colors  = (const float*)d_in[3];
    float* out = (float*)d_out;

    dim3 grid(IMG / TW, IMG / TH);  // 16 x 64 = 1024 blocks
    dim3 block(256);
    patch_dots_kernel<<<grid, block, 0, stream>>>(patch, centers, radii, colors, out);
}

// Round 3
// 310.378 us; speedup vs baseline: 1.0126x; 1.0126x over previous
//
#include <hip/hip_runtime.h>

// PatchTrainer: paint 100 filled circles (last-wins) over a 3x4096x4096 fp32 image.
// Per pixel: out = colors[max covering dot] else patch. Tile-culled, write-streaming.
// R4: descending scan + wave early-exit  -> NEUTRAL (dot loop not the bottleneck).
// R5: store-path levers:
//     (a) drop nontemporal stores (plain global_store_dwordx4; fills hit 6.5 TB/s
//         with plain stores, nt was never A/B'd),
//     (b) TH 64->32: 2048 blocks = 8/CU for tail smoothing + more outstanding stores,
//     (c) ballot-based ordered compaction replaces serial t==0 loop (100 dependent
//         LDS iterations -> ~20 instrs across 2 waves).

#define IMG  4096
#define ND   100
#define TW   256   // tile width  (64 lanes x float4 = one full row per wave)
#define TH   32    // tile height (4 waves, 8 iterations of 4 rows)

typedef float vfloat4 __attribute__((ext_vector_type(4)));

__global__ __launch_bounds__(256) void patch_dots_kernel(
    const float* __restrict__ patch,    // [3][4096][4096]
    const float* __restrict__ centers,  // [100][2] (x, y)
    const float* __restrict__ radii,    // [100]
    const float* __restrict__ colors,   // [100][3]
    float* __restrict__ out)            // [3][4096][4096]
{
    __shared__ float  s_xc[ND], s_yc[ND], s_r2[ND];
    __shared__ float4 s_col[ND];
    __shared__ int    s_list[ND];
    __shared__ unsigned long long s_mask[2];
    __shared__ int    s_cnt;

    const int tx0 = blockIdx.x * TW;
    const int ty0 = blockIdx.y * TH;
    const int t   = threadIdx.x;
    const int lane = t & 63;
    const int w    = t >> 6;

    // Stage dot params in LDS + tile-intersection cull (flag in registers).
    int flag = 0;
    if (t < ND) {
        // Bit-exact replication of the reference's fp32 math:
        float xc = floorf(centers[2 * t]     * 4096.0f);
        float yc = floorf(centers[2 * t + 1] * 4096.0f);
        float r  = floorf(radii[t] * (4096.0f / 5.0f));
        float r2 = r * r;
        s_xc[t] = xc; s_yc[t] = yc; s_r2[t] = r2;
        s_col[t] = make_float4(colors[3 * t], colors[3 * t + 1], colors[3 * t + 2], 0.f);
        // Nearest pixel of this tile to the (integer-valued) center:
        float cx = fminf(fmaxf(xc, (float)tx0), (float)(tx0 + TW - 1));
        float cy = fminf(fmaxf(yc, (float)ty0), (float)(ty0 + TH - 1));
        float dx = xc - cx, dy = yc - cy;
        flag = (dx * dx + dy * dy <= r2) ? 1 : 0;
    }
    // Ordered compaction via ballot (waves 0,1 hold dots 0..63, 64..99).
    if (t < 128) {
        unsigned long long m = __ballot(flag != 0);
        if (lane == 0) s_mask[w] = m;
    }
    __syncthreads();
    {
        const unsigned long long m0 = s_mask[0];
        if (flag) {
            const unsigned long long mw = s_mask[w];
            int pos = __popcll(mw & ((1ull << lane) - 1)) + (w ? __popcll(m0) : 0);
            s_list[pos] = t;
        }
        if (t == 0) s_cnt = __popcll(m0) + __popcll(s_mask[1]);
    }
    __syncthreads();
    const int cnt = s_cnt;

    const int x0   = tx0 + lane * 4;
    const float fx0 = (float)x0;
    const float fx1 = (float)(x0 + 1);
    const float fx2 = (float)(x0 + 2);
    const float fx3 = (float)(x0 + 3);

    for (int it = 0; it < TH / 4; ++it) {
        const int   y  = ty0 + it * 4 + w;
        const float fy = (float)y;

        // Scan dots from HIGHEST index down: first hit == last-drawn winner.
        int b0 = -1, b1 = -1, b2 = -1, b3 = -1;
        for (int k = cnt - 1; k >= 0; --k) {
            const int   i  = s_list[k];
            const float dy = fy - s_yc[i];
            // hit iff dx*dx <= r2 - dy*dy (exact-integer fp32 region: equivalent
            // to dx*dx + dy*dy <= r2, the reference's comparison)
            const float t2 = s_r2[i] - dy * dy;
            if (t2 < 0.f) continue;          // y uniform per wave -> coherent skip
            const float xc = s_xc[i];
            const float dx0 = fx0 - xc;
            const float dx1 = fx1 - xc;
            const float dx2 = fx2 - xc;
            const float dx3 = fx3 - xc;
            if (b0 < 0 && dx0 * dx0 <= t2) b0 = i;
            if (b1 < 0 && dx1 * dx1 <= t2) b1 = i;
            if (b2 < 0 && dx2 * dx2 <= t2) b2 = i;
            if (b3 < 0 && dx3 * dx3 <= t2) b3 = i;
            if (__all((b0 | b1 | b2 | b3) >= 0)) break;
        }

        const size_t base = (size_t)y * IMG + x0;

        // Patch only needed where no dot covers (rare: ~1.5% of pixels).
        float4 p0 = make_float4(0.f, 0.f, 0.f, 0.f);
        float4 p1 = p0, p2 = p0;
        if ((b0 | b1 | b2 | b3) < 0) {   // any of the 4 pixels uncovered
            p0 = *(const float4*)(patch + base);
            p1 = *(const float4*)(patch + base + (size_t)IMG * IMG);
            p2 = *(const float4*)(patch + base + 2 * (size_t)IMG * IMG);
        }

        const float4 c0 = (b0 >= 0) ? s_col[b0] : make_float4(p0.x, p1.x, p2.x, 0.f);
        const float4 c1 = (b1 >= 0) ? s_col[b1] : make_float4(p0.y, p1.y, p2.y, 0.f);
        const float4 c2 = (b2 >= 0) ? s_col[b2] : make_float4(p0.z, p1.z, p2.z, 0.f);
        const float4 c3 = (b3 >= 0) ? s_col[b3] : make_float4(p0.w, p1.w, p2.w, 0.f);

        vfloat4 o0, o1, o2;
        o0.x = c0.x; o0.y = c1.x; o0.z = c2.x; o0.w = c3.x;
        o1.x = c0.y; o1.y = c1.y; o1.z = c2.y; o1.w = c3.y;
        o2.x = c0.z; o2.y = c1.z; o2.z = c2.z; o2.w = c3.z;

        // Plain streaming stores (R5a: nontemporal dropped for A/B).
        *(vfloat4*)(out + base)                          = o0;
        *(vfloat4*)(out + base + (size_t)IMG * IMG)      = o1;
        *(vfloat4*)(out + base + 2 * (size_t)IMG * IMG)  = o2;
    }
}

extern "C" void kernel_launch(void* const* d_in, const int* in_sizes, int n_in,
                              void* d_out, int out_size, void* d_ws, size_t ws_size,
                              hipStream_t stream) {
    const float* patch   = (const float*)d_in[0];
    const float* centers = (const float*)d_in[1];
    const float* radii   = (const float*)d_in[2];
    const float* colors  = (const float*)d_in[3];
    float* out = (float*)d_out;

    dim3 grid(IMG / TW, IMG / TH);  // 16 x 128 = 2048 blocks (8/CU)
    dim3 block(256);
    patch_dots_kernel<<<grid, block, 0, stream>>>(patch, centers, radii, colors, out);
}

// Round 6
// 308.341 us; speedup vs baseline: 1.0193x; 1.0066x over previous
//
#include <hip/hip_runtime.h>

// PatchTrainer: paint 100 filled circles (last-wins) over a 3x4096x4096 fp32 image.
// Per pixel: out = colors[max covering dot] else patch. Tile-culled, write-streaming.
// R4: descending scan + wave early-exit       -> NEUTRAL (loop not the bottleneck)
// R5: plain stores, 8/CU, ballot compaction   -> ~NEUTRAL (-4 us)
// R6: plane-per-block; 2x infra failures with grid.z=3 -> R6b flattens to a 1D
//     grid (defensive: removes the only harness-facing novelty) while keeping
//     the experiment identical: each block writes ONE plane's tile as a single
//     sequential stream; plane = bid / (16*128), x-ascending dispatch => plane 0
//     blocks first => planes phase-separated device-wide. Tests: 3-way
//     plane-interleaved store streams throttle DRAM page locality (fill kernel =
//     1 stream = 6.5 TB/s; us = ~3 TB/s).

#define IMG  4096
#define ND   100
#define TW   256   // tile width  (64 lanes x float4 = one full row per wave)
#define TH   32    // tile height (4 waves, 8 iterations of 4 rows)
#define NBX  (IMG / TW)          // 16
#define NBY  (IMG / TH)          // 128

typedef float vfloat4 __attribute__((ext_vector_type(4)));

__global__ __launch_bounds__(256) void patch_dots_kernel(
    const float* __restrict__ patch,    // [3][4096][4096]
    const float* __restrict__ centers,  // [100][2] (x, y)
    const float* __restrict__ radii,    // [100]
    const float* __restrict__ colors,   // [100][3]
    float* __restrict__ out)            // [3][4096][4096]
{
    __shared__ float  s_xc[ND], s_yc[ND], s_r2[ND], s_col[ND];
    __shared__ int    s_list[ND];
    __shared__ unsigned long long s_mask[2];
    __shared__ int    s_cnt;

    // 1D grid decode: x fastest, then y-tile, plane slowest (phase-separated).
    const int bid = blockIdx.x;
    const int bx  = bid % NBX;
    const int by  = (bid / NBX) % NBY;
    const int z   = bid / (NBX * NBY);   // color plane

    const int tx0 = bx * TW;
    const int ty0 = by * TH;
    const int t   = threadIdx.x;
    const int lane = t & 63;
    const int w    = t >> 6;

    const size_t plane = (size_t)z * IMG * IMG;

    // Stage dot params in LDS + tile-intersection cull (flag in registers).
    int flag = 0;
    if (t < ND) {
        // Bit-exact replication of the reference's fp32 math:
        float xc = floorf(centers[2 * t]     * 4096.0f);
        float yc = floorf(centers[2 * t + 1] * 4096.0f);
        float r  = floorf(radii[t] * (4096.0f / 5.0f));
        float r2 = r * r;
        s_xc[t] = xc; s_yc[t] = yc; s_r2[t] = r2;
        s_col[t] = colors[3 * t + z];
        // Nearest pixel of this tile to the (integer-valued) center:
        float cx = fminf(fmaxf(xc, (float)tx0), (float)(tx0 + TW - 1));
        float cy = fminf(fmaxf(yc, (float)ty0), (float)(ty0 + TH - 1));
        float dx = xc - cx, dy = yc - cy;
        flag = (dx * dx + dy * dy <= r2) ? 1 : 0;
    }
    // Ordered compaction via ballot (waves 0,1 hold dots 0..63, 64..99).
    if (t < 128) {
        unsigned long long m = __ballot(flag != 0);
        if (lane == 0) s_mask[w] = m;
    }
    __syncthreads();
    {
        const unsigned long long m0 = s_mask[0];
        if (flag) {
            const unsigned long long mw = s_mask[w];
            int pos = __popcll(mw & ((1ull << lane) - 1)) + (w ? __popcll(m0) : 0);
            s_list[pos] = t;
        }
        if (t == 0) s_cnt = __popcll(m0) + __popcll(s_mask[1]);
    }
    __syncthreads();
    const int cnt = s_cnt;

    const int x0   = tx0 + lane * 4;
    const float fx0 = (float)x0;
    const float fx1 = (float)(x0 + 1);
    const float fx2 = (float)(x0 + 2);
    const float fx3 = (float)(x0 + 3);

    for (int it = 0; it < TH / 4; ++it) {
        const int   y  = ty0 + it * 4 + w;
        const float fy = (float)y;

        // Scan dots from HIGHEST index down: first hit == last-drawn winner.
        int b0 = -1, b1 = -1, b2 = -1, b3 = -1;
        for (int k = cnt - 1; k >= 0; --k) {
            const int   i  = s_list[k];
            const float dy = fy - s_yc[i];
            // hit iff dx*dx <= r2 - dy*dy (exact-integer fp32 region: equivalent
            // to dx*dx + dy*dy <= r2, the reference's comparison)
            const float t2 = s_r2[i] - dy * dy;
            if (t2 < 0.f) continue;          // y uniform per wave -> coherent skip
            const float xc = s_xc[i];
            const float dx0 = fx0 - xc;
            const float dx1 = fx1 - xc;
            const float dx2 = fx2 - xc;
            const float dx3 = fx3 - xc;
            if (b0 < 0 && dx0 * dx0 <= t2) b0 = i;
            if (b1 < 0 && dx1 * dx1 <= t2) b1 = i;
            if (b2 < 0 && dx2 * dx2 <= t2) b2 = i;
            if (b3 < 0 && dx3 * dx3 <= t2) b3 = i;
            if (__all((b0 | b1 | b2 | b3) >= 0)) break;
        }

        const size_t base = plane + (size_t)y * IMG + x0;

        // Patch (this plane only) needed where no dot covers (~1.5% of pixels).
        float4 p = make_float4(0.f, 0.f, 0.f, 0.f);
        if ((b0 | b1 | b2 | b3) < 0)
            p = *(const float4*)(patch + base);

        vfloat4 o;
        o.x = (b0 >= 0) ? s_col[b0] : p.x;
        o.y = (b1 >= 0) ? s_col[b1] : p.y;
        o.z = (b2 >= 0) ? s_col[b2] : p.z;
        o.w = (b3 >= 0) ? s_col[b3] : p.w;

        *(vfloat4*)(out + base) = o;
    }
}

extern "C" void kernel_launch(void* const* d_in, const int* in_sizes, int n_in,
                              void* d_out, int out_size, void* d_ws, size_t ws_size,
                              hipStream_t stream) {
    const float* patch   = (const float*)d_in[0];
    const float* centers = (const float*)d_in[1];
    const float* radii   = (const float*)d_in[2];
    const float* colors  = (const float*)d_in[3];
    float* out = (float*)d_out;

    dim3 grid(NBX * NBY * 3);  // 6144 blocks (24/CU), 1D
    dim3 block(256);
    patch_dots_kernel<<<grid, block, 0, stream>>>(patch, centers, radii, colors, out);
}

// Round 7
// 304.366 us; speedup vs baseline: 1.0326x; 1.0131x over previous
//
#include <hip/hip_runtime.h>

// PatchTrainer: paint 100 filled circles (last-wins) over a 3x4096x4096 fp32 image.
// Per pixel: out = colors[max covering dot] else patch. Tile-culled, write-streaming.
// R4: descending scan + wave early-exit       -> NEUTRAL (loop not the bottleneck)
// R5: plain stores, 8/CU, ballot compaction   -> ~NEUTRAL (-4 us, confounded A/B)
// R6b: plane-per-block, 1D grid, 24/CU        -> ~NEUTRAL (-2 us)
// R7: SINGLE-CHANGE A/B: nontemporal stores (+nt patch loads) on the R6b kernel.
//     Theory: plain stores trigger L2 write-allocate/RFO -> ~201MB hidden HBM
//     *read* traffic alongside the 201MB write stream (402MB @6.5TB/s = 62us ~=
//     the observed 64us kernel share). rocclr's fill uses a streaming-store path
//     and hits 6.5TB/s. nt bypasses L2 allocation for the write-once stream.

#define IMG  4096
#define ND   100
#define TW   256   // tile width  (64 lanes x float4 = one full row per wave)
#define TH   32    // tile height (4 waves, 8 iterations of 4 rows)
#define NBX  (IMG / TW)          // 16
#define NBY  (IMG / TH)          // 128

typedef float vfloat4 __attribute__((ext_vector_type(4)));

__global__ __launch_bounds__(256) void patch_dots_kernel(
    const float* __restrict__ patch,    // [3][4096][4096]
    const float* __restrict__ centers,  // [100][2] (x, y)
    const float* __restrict__ radii,    // [100]
    const float* __restrict__ colors,   // [100][3]
    float* __restrict__ out)            // [3][4096][4096]
{
    __shared__ float  s_xc[ND], s_yc[ND], s_r2[ND], s_col[ND];
    __shared__ int    s_list[ND];
    __shared__ unsigned long long s_mask[2];
    __shared__ int    s_cnt;

    // 1D grid decode: x fastest, then y-tile, plane slowest (phase-separated).
    const int bid = blockIdx.x;
    const int bx  = bid % NBX;
    const int by  = (bid / NBX) % NBY;
    const int z   = bid / (NBX * NBY);   // color plane

    const int tx0 = bx * TW;
    const int ty0 = by * TH;
    const int t   = threadIdx.x;
    const int lane = t & 63;
    const int w    = t >> 6;

    const size_t plane = (size_t)z * IMG * IMG;

    // Stage dot params in LDS + tile-intersection cull (flag in registers).
    int flag = 0;
    if (t < ND) {
        // Bit-exact replication of the reference's fp32 math:
        float xc = floorf(centers[2 * t]     * 4096.0f);
        float yc = floorf(centers[2 * t + 1] * 4096.0f);
        float r  = floorf(radii[t] * (4096.0f / 5.0f));
        float r2 = r * r;
        s_xc[t] = xc; s_yc[t] = yc; s_r2[t] = r2;
        s_col[t] = colors[3 * t + z];
        // Nearest pixel of this tile to the (integer-valued) center:
        float cx = fminf(fmaxf(xc, (float)tx0), (float)(tx0 + TW - 1));
        float cy = fminf(fmaxf(yc, (float)ty0), (float)(ty0 + TH - 1));
        float dx = xc - cx, dy = yc - cy;
        flag = (dx * dx + dy * dy <= r2) ? 1 : 0;
    }
    // Ordered compaction via ballot (waves 0,1 hold dots 0..63, 64..99).
    if (t < 128) {
        unsigned long long m = __ballot(flag != 0);
        if (lane == 0) s_mask[w] = m;
    }
    __syncthreads();
    {
        const unsigned long long m0 = s_mask[0];
        if (flag) {
            const unsigned long long mw = s_mask[w];
            int pos = __popcll(mw & ((1ull << lane) - 1)) + (w ? __popcll(m0) : 0);
            s_list[pos] = t;
        }
        if (t == 0) s_cnt = __popcll(m0) + __popcll(s_mask[1]);
    }
    __syncthreads();
    const int cnt = s_cnt;

    const int x0   = tx0 + lane * 4;
    const float fx0 = (float)x0;
    const float fx1 = (float)(x0 + 1);
    const float fx2 = (float)(x0 + 2);
    const float fx3 = (float)(x0 + 3);

    for (int it = 0; it < TH / 4; ++it) {
        const int   y  = ty0 + it * 4 + w;
        const float fy = (float)y;

        // Scan dots from HIGHEST index down: first hit == last-drawn winner.
        int b0 = -1, b1 = -1, b2 = -1, b3 = -1;
        for (int k = cnt - 1; k >= 0; --k) {
            const int   i  = s_list[k];
            const float dy = fy - s_yc[i];
            // hit iff dx*dx <= r2 - dy*dy (exact-integer fp32 region: equivalent
            // to dx*dx + dy*dy <= r2, the reference's comparison)
            const float t2 = s_r2[i] - dy * dy;
            if (t2 < 0.f) continue;          // y uniform per wave -> coherent skip
            const float xc = s_xc[i];
            const float dx0 = fx0 - xc;
            const float dx1 = fx1 - xc;
            const float dx2 = fx2 - xc;
            const float dx3 = fx3 - xc;
            if (b0 < 0 && dx0 * dx0 <= t2) b0 = i;
            if (b1 < 0 && dx1 * dx1 <= t2) b1 = i;
            if (b2 < 0 && dx2 * dx2 <= t2) b2 = i;
            if (b3 < 0 && dx3 * dx3 <= t2) b3 = i;
            if (__all((b0 | b1 | b2 | b3) >= 0)) break;
        }

        const size_t base = plane + (size_t)y * IMG + x0;

        // Patch (this plane only) needed where no dot covers (~1.5% of pixels).
        // Read-once data: nontemporal to avoid polluting L2.
        float4 p = make_float4(0.f, 0.f, 0.f, 0.f);
        if ((b0 | b1 | b2 | b3) < 0) {
            const vfloat4 pv = __builtin_nontemporal_load((const vfloat4*)(patch + base));
            p = make_float4(pv.x, pv.y, pv.z, pv.w);
        }

        vfloat4 o;
        o.x = (b0 >= 0) ? s_col[b0] : p.x;
        o.y = (b1 >= 0) ? s_col[b1] : p.y;
        o.z = (b2 >= 0) ? s_col[b2] : p.z;
        o.w = (b3 >= 0) ? s_col[b3] : p.w;

        // R7: nontemporal store — bypass L2 write-allocate (RFO) for the
        // write-once 201MB stream.
        __builtin_nontemporal_store(o, (vfloat4*)(out + base));
    }
}

extern "C" void kernel_launch(void* const* d_in, const int* in_sizes, int n_in,
                              void* d_out, int out_size, void* d_ws, size_t ws_size,
                              hipStream_t stream) {
    const float* patch   = (const float*)d_in[0];
    const float* centers = (const float*)d_in[1];
    const float* radii   = (const float*)d_in[2];
    const float* colors  = (const float*)d_in[3];
    float* out = (float*)d_out;

    dim3 grid(NBX * NBY * 3);  // 6144 blocks, 1D
    dim3 block(256);
    patch_dots_kernel<<<grid, block, 0, stream>>>(patch, centers, radii, colors, out);
}